// Round 1
// baseline (2582.680 us; speedup 1.0000x reference)
//
#include <hip/hip_runtime.h>

#define SEQ 49
#define CH 384
#define NH 12
#define HD 32
#define NWIN 1024
#define TC 1152
#define MTOT 401408   // 8192*49

typedef short bf16x8 __attribute__((ext_vector_type(8)));
typedef float f32x4 __attribute__((ext_vector_type(4)));

__device__ __forceinline__ short f2bf(float f) {
  union { float f; unsigned u; } v; v.f = f;
  unsigned r = v.u + 0x7fffu + ((v.u >> 16) & 1u);   // RNE
  return (short)(r >> 16);
}

// ---------------- K0: weight convert+transpose to bf16 wT[n][k] ----------------
__global__ __launch_bounds__(256) void wconv(const float* __restrict__ qkv_w,
    const float* __restrict__ proj_w, short* __restrict__ qkv_wT,
    short* __restrict__ proj_wT) {
  int id = blockIdx.x * 256 + threadIdx.x;
  if (id < TC * CH) {
    int j = id / CH, c = id - j * CH;
    qkv_wT[id] = f2bf(qkv_w[(size_t)c * TC + j]);
  } else {
    int id2 = id - TC * CH;
    int j = id2 / CH, c = id2 - j * CH;
    proj_wT[id2] = f2bf(proj_w[(size_t)c * CH + j]);
  }
}

// ---------------- K1: QKV GEMM (M=401408, K=384, N=1152) ----------------
// writes q (scaled, bf16, (w,h,n,d)) , k (bf16, (w,h,n,d)), vT (bf16, (w,h,d,n) pad n->56)
__global__ __launch_bounds__(256) void qkv_gemm(const float* __restrict__ x,
    const short* __restrict__ wT, const float* __restrict__ bias,
    short* __restrict__ q_all, short* __restrict__ k_all, short* __restrict__ vT_all) {
  __shared__ short As[128 * 72];   // [m][k] pad 64->72 (2-way bank conflicts only)
  __shared__ short Bs[128 * 72];   // [n][k]
  int b = blockIdx.x;
  int xcd = b & 7, jj = b >> 3;            // XCD-swizzle: col-tiles innermost per XCD
  int rt = xcd * 392 + jj / 9;             // 3136 row tiles = 8*392
  int ct = jj % 9;                         // 9 col tiles of 128 (q:0-2 k:3-5 v:6-8)
  int row0 = rt << 7, col0 = ct << 7;
  int tid = threadIdx.x;
  int wv = tid >> 6, lane = tid & 63;
  int q2 = lane >> 4, ln = lane & 15;
  int wr = (wv >> 1) << 6, wc = (wv & 1) << 6;   // wave quadrant (64x64)

  f32x4 acc[4][4];
  const f32x4 zz = {0.f, 0.f, 0.f, 0.f};
  #pragma unroll
  for (int i = 0; i < 4; ++i)
    #pragma unroll
    for (int j = 0; j < 4; ++j) acc[i][j] = zz;

  for (int kc = 0; kc < 6; ++kc) {
    int k0 = kc << 6;
    #pragma unroll
    for (int it = 0; it < 8; ++it) {       // A: 128x64 fp32 -> bf16
      int lin = it * 256 + tid;
      int r = lin >> 4, c4 = (lin & 15) << 2;
      float4 f = *(const float4*)(x + (size_t)(row0 + r) * CH + k0 + c4);
      ushort4 hh;
      hh.x = (unsigned short)f2bf(f.x); hh.y = (unsigned short)f2bf(f.y);
      hh.z = (unsigned short)f2bf(f.z); hh.w = (unsigned short)f2bf(f.w);
      *(ushort4*)&As[r * 72 + c4] = hh;
    }
    #pragma unroll
    for (int it = 0; it < 4; ++it) {       // B: 128x64 bf16
      int lin = it * 256 + tid;
      int r = lin >> 3, c8 = (lin & 7) << 3;
      *(bf16x8*)&Bs[r * 72 + c8] = *(const bf16x8*)(wT + (size_t)(col0 + r) * CH + k0 + c8);
    }
    __syncthreads();
    #pragma unroll
    for (int ks = 0; ks < 2; ++ks) {
      int kk = ks * 32 + q2 * 8;
      bf16x8 af[4], bfr[4];
      #pragma unroll
      for (int t = 0; t < 4; ++t) af[t] = *(const bf16x8*)&As[(wr + t * 16 + ln) * 72 + kk];
      #pragma unroll
      for (int t = 0; t < 4; ++t) bfr[t] = *(const bf16x8*)&Bs[(wc + t * 16 + ln) * 72 + kk];
      #pragma unroll
      for (int i = 0; i < 4; ++i)
        #pragma unroll
        for (int j = 0; j < 4; ++j)
          acc[i][j] = __builtin_amdgcn_mfma_f32_16x16x32_bf16(af[i], bfr[j], acc[i][j], 0, 0, 0);
    }
    __syncthreads();
  }

  float bv[4]; int hh4[4], dd4[4];
  #pragma unroll
  for (int j = 0; j < 4; ++j) {
    int c = col0 + wc + j * 16 + ln;       // global col in [0,1152)
    bv[j] = bias[c];
    int cc = c - (c >= 768 ? 768 : (c >= 384 ? 384 : 0));
    hh4[j] = cc >> 5; dd4[j] = cc & 31;
  }
  const float scale = 0.17677669529663687f;  // hd^-0.5 folded into q
  #pragma unroll
  for (int i = 0; i < 4; ++i) {
    #pragma unroll
    for (int r = 0; r < 4; ++r) {
      int m = row0 + wr + i * 16 + q2 * 4 + r;  // C/D layout: row=quad*4+reg
      int w = m / SEQ;
      int n = m - w * SEQ;
      int whb = w * NH;
      #pragma unroll
      for (int j = 0; j < 4; ++j) {
        float val = acc[i][j][r] + bv[j];
        if (ct < 3) {
          q_all[((size_t)(whb + hh4[j]) * SEQ + n) * HD + dd4[j]] = f2bf(val * scale);
        } else if (ct < 6) {
          k_all[((size_t)(whb + hh4[j]) * SEQ + n) * HD + dd4[j]] = f2bf(val);
        } else {
          vT_all[((size_t)(whb + hh4[j]) * HD + dd4[j]) * 56 + n] = f2bf(val);
        }
      }
    }
  }
}

// ---------------- K2: windowed attention, one wave per (window, head) ----------------
__global__ __launch_bounds__(256) void attn_kernel(const short* __restrict__ q_all,
    const short* __restrict__ k_all, const short* __restrict__ vT_all,
    const float* __restrict__ rel_bias, const float* __restrict__ mask,
    short* __restrict__ attn_out) {
  __shared__ short Pl[4 * 64 * 72];        // per-wave P tile, A-operand layout
  int tid = threadIdx.x;
  int wv = tid >> 6, lane = tid & 63;
  int q2 = lane >> 4, ln = lane & 15;
  int wh = blockIdx.x * 4 + wv;            // 0..98303
  int w = wh / NH, h = wh - w * NH;
  int wi = w & (NWIN - 1);
  const short* qb = q_all + (size_t)wh * (SEQ * HD);
  const short* kb = k_all + (size_t)wh * (SEQ * HD);
  const short* vb = vT_all + (size_t)wh * (HD * 56);

  // QK^T: M=64(pad) N=64(pad) K=32, fragments straight from global (rows clamped)
  bf16x8 aq[4], bk[4];
  #pragma unroll
  for (int t = 0; t < 4; ++t) {
    int m = t * 16 + ln;
    int mc = m < SEQ ? m : SEQ - 1;
    aq[t] = *(const bf16x8*)(qb + mc * HD + q2 * 8);
    bk[t] = *(const bf16x8*)(kb + mc * HD + q2 * 8);
  }
  const f32x4 zz = {0.f, 0.f, 0.f, 0.f};
  f32x4 s[4][4];
  #pragma unroll
  for (int i = 0; i < 4; ++i)
    #pragma unroll
    for (int j = 0; j < 4; ++j)
      s[i][j] = __builtin_amdgcn_mfma_f32_16x16x32_bf16(aq[i], bk[j], zz, 0, 0, 0);

  const float* bias_b = rel_bias + h * (SEQ * SEQ);
  const float* mask_b = mask + wi * (SEQ * SEQ);
  #pragma unroll
  for (int i = 0; i < 4; ++i) {
    #pragma unroll
    for (int r = 0; r < 4; ++r) {
      int m = i * 16 + q2 * 4 + r;
      int mc = m < SEQ ? m : SEQ - 1;
      float v4[4]; float mx = -1e30f;
      #pragma unroll
      for (int j = 0; j < 4; ++j) {
        int n = j * 16 + ln;
        float t = -1e30f;
        if (n < SEQ) t = s[i][j][r] + bias_b[mc * SEQ + n] + mask_b[mc * SEQ + n];
        v4[j] = t; mx = fmaxf(mx, t);
      }
      #pragma unroll
      for (int off = 1; off < 16; off <<= 1) mx = fmaxf(mx, __shfl_xor(mx, off));
      float sum = 0.f;
      #pragma unroll
      for (int j = 0; j < 4; ++j) {
        float e = (v4[j] > -1e29f) ? exp2f((v4[j] - mx) * 1.4426950408889634f) : 0.f;
        v4[j] = e; sum += e;
      }
      #pragma unroll
      for (int off = 1; off < 16; off <<= 1) sum += __shfl_xor(sum, off);
      float is = 1.f / sum;
      #pragma unroll
      for (int j = 0; j < 4; ++j)
        Pl[wv * 4608 + m * 72 + j * 16 + ln] = f2bf(v4[j] * is);  // cols>=49 are 0
    }
  }
  __syncthreads();

  // PV: M=64(pad) N=32 K=64(pad, P cols>=49 are zero)
  f32x4 o[4][2];
  #pragma unroll
  for (int i = 0; i < 4; ++i) { o[i][0] = zz; o[i][1] = zz; }
  #pragma unroll
  for (int ks = 0; ks < 2; ++ks) {
    int kk = ks * 32 + q2 * 8;
    bf16x8 ap[4], bvv[2];
    #pragma unroll
    for (int t = 0; t < 4; ++t) ap[t] = *(const bf16x8*)&Pl[wv * 4608 + (t * 16 + ln) * 72 + kk];
    #pragma unroll
    for (int t = 0; t < 2; ++t) bvv[t] = *(const bf16x8*)(vb + (t * 16 + ln) * 56 + kk);
    #pragma unroll
    for (int i = 0; i < 4; ++i)
      #pragma unroll
      for (int j = 0; j < 2; ++j)
        o[i][j] = __builtin_amdgcn_mfma_f32_16x16x32_bf16(ap[i], bvv[j], o[i][j], 0, 0, 0);
  }
  int wn0 = w * SEQ;
  #pragma unroll
  for (int i = 0; i < 4; ++i) {
    #pragma unroll
    for (int r = 0; r < 4; ++r) {
      int nrow = i * 16 + q2 * 4 + r;
      if (nrow < SEQ) {
        size_t off = (size_t)(wn0 + nrow) * CH + h * HD;
        #pragma unroll
        for (int j = 0; j < 2; ++j)
          attn_out[off + j * 16 + ln] = f2bf(o[i][j][r]);
      }
    }
  }
}

// ---------------- K3: output projection (M=401408, K=384, N=384) ----------------
__global__ __launch_bounds__(256) void proj_gemm(const short* __restrict__ attn,
    const short* __restrict__ wT, const float* __restrict__ bias,
    float* __restrict__ out) {
  __shared__ short As[128 * 72];
  __shared__ short Bs[128 * 72];
  int b = blockIdx.x;
  int xcd = b & 7, jj = b >> 3;
  int rt = xcd * 392 + jj / 3;
  int ct = jj % 3;
  int row0 = rt << 7, col0 = ct << 7;
  int tid = threadIdx.x;
  int wv = tid >> 6, lane = tid & 63;
  int q2 = lane >> 4, ln = lane & 15;
  int wr = (wv >> 1) << 6, wc = (wv & 1) << 6;

  f32x4 acc[4][4];
  const f32x4 zz = {0.f, 0.f, 0.f, 0.f};
  #pragma unroll
  for (int i = 0; i < 4; ++i)
    #pragma unroll
    for (int j = 0; j < 4; ++j) acc[i][j] = zz;

  for (int kc = 0; kc < 6; ++kc) {
    int k0 = kc << 6;
    #pragma unroll
    for (int it = 0; it < 4; ++it) {
      int lin = it * 256 + tid;
      int r = lin >> 3, c8 = (lin & 7) << 3;
      *(bf16x8*)&As[r * 72 + c8] = *(const bf16x8*)(attn + (size_t)(row0 + r) * CH + k0 + c8);
      *(bf16x8*)&Bs[r * 72 + c8] = *(const bf16x8*)(wT + (size_t)(col0 + r) * CH + k0 + c8);
    }
    __syncthreads();
    #pragma unroll
    for (int ks = 0; ks < 2; ++ks) {
      int kk = ks * 32 + q2 * 8;
      bf16x8 af[4], bfr[4];
      #pragma unroll
      for (int t = 0; t < 4; ++t) af[t] = *(const bf16x8*)&As[(wr + t * 16 + ln) * 72 + kk];
      #pragma unroll
      for (int t = 0; t < 4; ++t) bfr[t] = *(const bf16x8*)&Bs[(wc + t * 16 + ln) * 72 + kk];
      #pragma unroll
      for (int i = 0; i < 4; ++i)
        #pragma unroll
        for (int j = 0; j < 4; ++j)
          acc[i][j] = __builtin_amdgcn_mfma_f32_16x16x32_bf16(af[i], bfr[j], acc[i][j], 0, 0, 0);
    }
    __syncthreads();
  }
  float bv[4];
  #pragma unroll
  for (int j = 0; j < 4; ++j) bv[j] = bias[col0 + wc + j * 16 + ln];
  #pragma unroll
  for (int i = 0; i < 4; ++i) {
    #pragma unroll
    for (int r = 0; r < 4; ++r) {
      int m = row0 + wr + i * 16 + q2 * 4 + r;
      #pragma unroll
      for (int j = 0; j < 4; ++j)
        out[(size_t)m * CH + col0 + wc + j * 16 + ln] = acc[i][j][r] + bv[j];
    }
  }
}

extern "C" void kernel_launch(void* const* d_in, const int* in_sizes, int n_in,
                              void* d_out, int out_size, void* d_ws, size_t ws_size,
                              hipStream_t stream) {
  const float* x        = (const float*)d_in[0];
  const float* mask     = (const float*)d_in[1];
  const float* qkv_w    = (const float*)d_in[2];
  const float* qkv_b    = (const float*)d_in[3];
  const float* rel_bias = (const float*)d_in[4];
  const float* proj_w   = (const float*)d_in[5];
  const float* proj_b   = (const float*)d_in[6];

  // ws layout: attn_out bf16 (308,281,344 B) | vT bf16 (352,321,536 B) | qkv_wT | proj_wT
  char* ws = (char*)d_ws;
  short* attn_ws = (short*)ws;
  short* vT      = (short*)(ws + 308281344ull);
  short* qkv_wT  = (short*)(ws + 308281344ull + 352321536ull);
  short* proj_wT = qkv_wT + (size_t)TC * CH;
  // d_out doubles as scratch for q,k (bf16, exactly fills the 616.6 MB) until proj_gemm
  short* q_all = (short*)d_out;
  short* k_all = q_all + (size_t)MTOT * CH;

  wconv<<<2304, 256, 0, stream>>>(qkv_w, proj_w, qkv_wT, proj_wT);
  qkv_gemm<<<28224, 256, 0, stream>>>(x, qkv_wT, qkv_b, q_all, k_all, vT);
  attn_kernel<<<24576, 256, 0, stream>>>(q_all, k_all, vT, rel_bias, mask, attn_ws);
  proj_gemm<<<9408, 256, 0, stream>>>(attn_ws, proj_wT, proj_b, (float*)d_out);
}